// Round 4
// baseline (170.264 us; speedup 1.0000x reference)
//
#include <hip/hip_runtime.h>
#include <hip/hip_bf16.h>

#define IN_FEAT 128
#define N_HEADS 4
#define OUT_FEAT 16
#define HF 64  // N_HEADS * OUT_FEAT
#define NEG_SLOPE 0.2f

#define BSHIFT 7                 // 128 nodes per bucket
#define BNODES 128
#define NBUCK_MAX 512            // >= ceil(50000/128)=391

typedef __hip_bfloat16 bf16;
typedef __attribute__((ext_vector_type(8))) short short8;
typedef __attribute__((ext_vector_type(4))) float f32x4;

__device__ inline unsigned short f2b(float f) {
  bf16 b = __float2bfloat16(f);
  return *(unsigned short*)&b;
}
__device__ inline float b2f(unsigned short u) {
  return __uint_as_float((unsigned)u << 16);
}
// Extract bf16 alpha for head sel (0..3) from packed {lo,hi} words.
__device__ inline float alpha_lane(unsigned lo, unsigned hi, unsigned sel) {
  unsigned wd = (sel & 2u) ? hi : lo;
  return __uint_as_float(((wd >> ((sel & 1u) * 16u)) & 0xffffu) << 16);
}

// ---------------------------------------------------------------------------
// Kernel 1: h = x @ W via bf16 MFMA + fused LDS bucket histogram (no global
// atomics). Block = 256 thr = 4 waves = 64 nodes. Edge chunking by blockIdx
// over the gemm grid (gb blocks) MUST match k_part.
// ---------------------------------------------------------------------------
__global__ __launch_bounds__(256) void k_gemm(
    const float* __restrict__ x, const float* __restrict__ W,
    const float* __restrict__ a, unsigned short* __restrict__ h16,
    float* __restrict__ e_src, float* __restrict__ e_dst,
    const int* __restrict__ dst, int* __restrict__ bh,
    int n_nodes, int n_edges, int nbuck, int chunkE, int gb) {
  __shared__ unsigned short xs[64][136];
  __shared__ unsigned short wt[64][136];
  __shared__ unsigned short sh[64][68];
  __shared__ int bhist[NBUCK_MAX];
  const int t = threadIdx.x;
  const int nb = blockIdx.x * 64;
  const int lane = t & 63;
  const int w = t >> 6;

  for (int i = t; i < NBUCK_MAX; i += 256) bhist[i] = 0;

  const float4* x4 = (const float4*)x;
  for (int i = t; i < 64 * 32; i += 256) {
    int n = i >> 5, k4 = i & 31;
    int gn = nb + n;
    float4 v = (gn < n_nodes) ? x4[(size_t)gn * 32 + k4]
                              : make_float4(0.f, 0.f, 0.f, 0.f);
    ushort4 u;
    u.x = f2b(v.x); u.y = f2b(v.y); u.z = f2b(v.z); u.w = f2b(v.w);
    *(ushort4*)&xs[n][k4 * 4] = u;
  }
  for (int i = t; i < IN_FEAT * HF; i += 256) {
    int k = i >> 6, c = i & 63;
    wt[c][k] = f2b(W[i]);
  }
  __syncthreads();

  const int m = lane & 15;
  const int q = lane >> 4;
  f32x4 acc[4];
#pragma unroll
  for (int nt = 0; nt < 4; ++nt) acc[nt] = (f32x4){0.f, 0.f, 0.f, 0.f};

#pragma unroll
  for (int kc = 0; kc < 4; ++kc) {
    short8 af = *(const short8*)&xs[w * 16 + m][kc * 32 + q * 8];
#pragma unroll
    for (int nt = 0; nt < 4; ++nt) {
      short8 bfr = *(const short8*)&wt[nt * 16 + m][kc * 32 + q * 8];
      acc[nt] = __builtin_amdgcn_mfma_f32_16x16x32_bf16(af, bfr, acc[nt], 0, 0, 0);
    }
  }

#pragma unroll
  for (int nt = 0; nt < 4; ++nt)
#pragma unroll
    for (int r = 0; r < 4; ++r)
      sh[w * 16 + q * 4 + r][nt * 16 + m] = f2b(acc[nt][r]);
  __syncthreads();

  {
    int n = t >> 2, hd = t & 3;
    int gn = nb + n;
    if (gn < n_nodes) {
      float es = 0.f, ed = 0.f;
#pragma unroll
      for (int f = 0; f < OUT_FEAT; ++f) {
        float hv = b2f(sh[n][hd * 16 + f]);
        es = fmaf(hv, a[hd * 2 * OUT_FEAT + f], es);
        ed = fmaf(hv, a[hd * 2 * OUT_FEAT + OUT_FEAT + f], ed);
      }
      e_src[gn * N_HEADS + hd] = es;
      e_dst[gn * N_HEADS + hd] = ed;
    }
  }

  for (int i = t; i < 64 * 16; i += 256) {
    int n = i >> 4, c4 = (i & 15) * 4;
    int gn = nb + n;
    if (gn < n_nodes) {
      ushort4 v;
      v.x = sh[n][c4 + 0]; v.y = sh[n][c4 + 1];
      v.z = sh[n][c4 + 2]; v.w = sh[n][c4 + 3];
      *(ushort4*)(h16 + (size_t)gn * HF + c4) = v;
    }
  }

  // Fused bucket histogram (LDS atomics only) on this block's edge chunk.
  {
    int ebeg = blockIdx.x * chunkE;
    int eend = min(ebeg + chunkE, n_edges);
    for (int e = ebeg + t; e < eend; e += 256)
      atomicAdd(&bhist[dst[e] >> BSHIFT], 1);
    __syncthreads();
    for (int k = t; k < nbuck; k += 256)
      bh[(size_t)k * gb + blockIdx.x] = bhist[k];
  }
}

// ---------------------------------------------------------------------------
// scanA: one block per bucket; parallel exclusive scan of bh[k][0..gb) over
// the gb edge-chunk blocks -> sbase[k][b], and bucket total -> tot[k].
// ---------------------------------------------------------------------------
__global__ __launch_bounds__(1024) void k_scanA(
    const int* __restrict__ bh, int* __restrict__ sbase, int* __restrict__ tot,
    int gb) {
  __shared__ int s[1024];
  int t = threadIdx.x, k = blockIdx.x;
  int v = (t < gb) ? bh[(size_t)k * gb + t] : 0;
  s[t] = v;
  __syncthreads();
  for (int off = 1; off < 1024; off <<= 1) {
    int u = (t >= off) ? s[t - off] : 0;
    __syncthreads();
    s[t] += u;
    __syncthreads();
  }
  if (t < gb) sbase[(size_t)k * gb + t] = s[t] - v;
  if (t == 1023) tot[k] = s[t];
}

// ---------------------------------------------------------------------------
// scanB: single block; exclusive scan of bucket totals -> bucket_base.
// ---------------------------------------------------------------------------
__global__ __launch_bounds__(512) void k_scanB(
    const int* __restrict__ tot, int* __restrict__ bucket_base,
    int* __restrict__ offsets, int nbuck, int n_edges, int n_nodes) {
  __shared__ int s[512];
  int t = threadIdx.x;
  int v = (t < nbuck) ? tot[t] : 0;
  s[t] = v;
  __syncthreads();
  for (int off = 1; off < 512; off <<= 1) {
    int u = (t >= off) ? s[t - off] : 0;
    __syncthreads();
    s[t] += u;
    __syncthreads();
  }
  if (t < nbuck) bucket_base[t] = s[t] - v;
  if (t == 0) {
    bucket_base[nbuck] = n_edges;
    offsets[n_nodes] = n_edges;
  }
}

// ---------------------------------------------------------------------------
// Partition: softmax alpha per edge, scatter one 16B record
// {src, d&127, alpha_lo, alpha_hi} to its bucket-exact slot. LDS cursors
// pre-reserved from bucket_base + sbase — ZERO global atomics. Same gb-block
// chunking as k_gemm's histogram.
// ---------------------------------------------------------------------------
__global__ __launch_bounds__(256) void k_part(
    const int* __restrict__ src, const int* __restrict__ dst,
    const float* __restrict__ e_src, const float* __restrict__ e_dst,
    const int* __restrict__ bucket_base, const int* __restrict__ sbase,
    uint4* __restrict__ recs, int nbuck, int chunkE, int n_edges, int gb) {
  __shared__ int cur[NBUCK_MAX];
  int t = threadIdx.x;
  for (int k = t; k < nbuck; k += 256)
    cur[k] = bucket_base[k] + sbase[(size_t)k * gb + blockIdx.x];
  __syncthreads();
  int beg = blockIdx.x * chunkE;
  int end = min(beg + chunkE, n_edges);
  for (int e = beg + t; e < end; e += 256) {
    int s = src[e], d = dst[e];
    float4 es = ((const float4*)e_src)[s];
    float4 ed = ((const float4*)e_dst)[d];
    float v0 = es.x + ed.x, v1 = es.y + ed.y, v2 = es.z + ed.z, v3 = es.w + ed.w;
    v0 = (v0 > 0.f) ? v0 : NEG_SLOPE * v0;
    v1 = (v1 > 0.f) ? v1 : NEG_SLOPE * v1;
    v2 = (v2 > 0.f) ? v2 : NEG_SLOPE * v2;
    v3 = (v3 > 0.f) ? v3 : NEG_SLOPE * v3;
    float m = fmaxf(fmaxf(v0, v1), fmaxf(v2, v3));
    float e0 = __expf(v0 - m), e1 = __expf(v1 - m);
    float e2 = __expf(v2 - m), e3 = __expf(v3 - m);
    float inv = 1.f / (e0 + e1 + e2 + e3);
    unsigned lo = (unsigned)f2b(e0 * inv) | ((unsigned)f2b(e1 * inv) << 16);
    unsigned hi = (unsigned)f2b(e2 * inv) | ((unsigned)f2b(e3 * inv) << 16);
    int pos = atomicAdd(&cur[d >> BSHIFT], 1);
    recs[pos] = make_uint4((unsigned)s, (unsigned)(d & (BNODES - 1)), lo, hi);
  }
}

// ---------------------------------------------------------------------------
// Within-bucket counting sort by 7-bit local dst: LDS 128-bin histogram +
// scan + scatter into combined 16B records sorted16 = {src,0,alpha_lo,hi};
// also emits per-node offsets. Scattered writes land in an L2-resident
// 32KB window. LDS atomics only.
// ---------------------------------------------------------------------------
__global__ __launch_bounds__(512) void k_sort(
    const uint4* __restrict__ recs, const int* __restrict__ bucket_base,
    uint4* __restrict__ sorted16, int* __restrict__ offsets,
    int nbuck, int n_nodes) {
  __shared__ int hist[BNODES];
  __shared__ int cur[BNODES];
  int t = threadIdx.x, k = blockIdx.x;
  int beg = bucket_base[k];
  int n = bucket_base[k + 1] - beg;
  if (t < BNODES) hist[t] = 0;
  __syncthreads();
  for (int j = t; j < n; j += 512)
    atomicAdd(&hist[recs[beg + j].y], 1);
  __syncthreads();
  int v = (t < BNODES) ? hist[t] : 0;
  for (int off = 1; off < BNODES; off <<= 1) {
    int u = (t < BNODES && t >= off) ? hist[t - off] : 0;
    __syncthreads();
    if (t < BNODES) hist[t] += u;
    __syncthreads();
  }
  if (t < BNODES) {
    int pos = beg + hist[t] - v;  // exclusive
    cur[t] = pos;
    int node = (k << BSHIFT) + t;
    if (node < n_nodes) offsets[node] = pos;
  }
  __syncthreads();
  for (int j = t; j < n; j += 512) {
    uint4 r = recs[beg + j];
    int p = atomicAdd(&cur[r.y], 1);
    sorted16[p] = make_uint4(r.x, 0u, r.z, r.w);
  }
}

// ---------------------------------------------------------------------------
// Gather: one wave per dst node, lane = feature. One 16B broadcast record
// load per edge + one coalesced 128B h16 row read per edge. Unroll x8.
// ---------------------------------------------------------------------------
__global__ __launch_bounds__(256) void k_gather(
    const uint4* __restrict__ sorted16, const int* __restrict__ offsets,
    const unsigned short* __restrict__ h16, float* __restrict__ out,
    int n_nodes) {
  int gid = blockIdx.x * 256 + threadIdx.x;
  int d = gid >> 6;
  int c = gid & 63;
  if (d >= n_nodes) return;
  int beg = offsets[d];
  int end = offsets[d + 1];
  unsigned sel = (unsigned)(c >> 4);
  float acc = 0.f;
  int j = beg;
  for (; j + 8 <= end; j += 8) {
    uint4 r[8];
    float hv[8];
#pragma unroll
    for (int k = 0; k < 8; ++k) r[k] = sorted16[j + k];
#pragma unroll
    for (int k = 0; k < 8; ++k) hv[k] = b2f(h16[(size_t)r[k].x * HF + c]);
#pragma unroll
    for (int k = 0; k < 8; ++k)
      acc = fmaf(alpha_lane(r[k].z, r[k].w, sel), hv[k], acc);
  }
  for (; j < end; ++j) {
    uint4 r = sorted16[j];
    acc = fmaf(alpha_lane(r.z, r.w, sel), b2f(h16[(size_t)r.x * HF + c]), acc);
  }
  out[(size_t)d * HF + c] = acc;
}

extern "C" void kernel_launch(void* const* d_in, const int* in_sizes, int n_in,
                              void* d_out, int out_size, void* d_ws, size_t ws_size,
                              hipStream_t stream) {
  const float* x = (const float*)d_in[0];
  const int* ei = (const int*)d_in[1];
  const float* W = (const float*)d_in[2];
  const float* a = (const float*)d_in[3];
  float* out = (float*)d_out;

  const int n_nodes = in_sizes[0] / IN_FEAT;   // 50000
  const int n_edges = in_sizes[1] / 2;         // 800000
  const int* src = ei;
  const int* dst = ei + n_edges;

  const int nbuck = (n_nodes + BNODES - 1) >> BSHIFT;   // 391 (<= NBUCK_MAX)
  const int gb = (n_nodes + 63) / 64;                   // 782 (<= 1024 for scanA)
  const int chunkE = (n_edges + gb - 1) / gb;           // 1024

  char* ws = (char*)d_ws;
  size_t off = 0;
  uint4* recs = (uint4*)(ws + off);        off += (size_t)n_edges * 16;           // 12.8 MB
  uint4* sorted16 = (uint4*)(ws + off);    off += (size_t)n_edges * 16;           // 12.8 MB
  unsigned short* h16 = (unsigned short*)(ws + off); off += (size_t)n_nodes * HF * 2; // 6.4 MB
  float* e_src = (float*)(ws + off);       off += (size_t)n_nodes * N_HEADS * 4;  // 0.8 MB
  float* e_dst = (float*)(ws + off);       off += (size_t)n_nodes * N_HEADS * 4;  // 0.8 MB
  int* bh = (int*)(ws + off);              off += (size_t)NBUCK_MAX * gb * 4;     // 1.6 MB
  int* sbase = (int*)(ws + off);           off += (size_t)NBUCK_MAX * gb * 4;     // 1.6 MB
  int* tot = (int*)(ws + off);             off += (size_t)NBUCK_MAX * 4;
  int* bucket_base = (int*)(ws + off);     off += (size_t)(NBUCK_MAX + 1) * 4;
  int* offsets = (int*)(ws + off);         off += ((size_t)n_nodes + 16) * 4;

  // Zero global atomics anywhere; no memsets (all buffers fully written
  // before read).
  k_gemm<<<gb, 256, 0, stream>>>(x, W, a, h16, e_src, e_dst, dst, bh,
                                 n_nodes, n_edges, nbuck, chunkE, gb);
  k_scanA<<<nbuck, 1024, 0, stream>>>(bh, sbase, tot, gb);
  k_scanB<<<1, 512, 0, stream>>>(tot, bucket_base, offsets, nbuck, n_edges, n_nodes);
  k_part<<<gb, 256, 0, stream>>>(src, dst, e_src, e_dst, bucket_base, sbase,
                                 recs, nbuck, chunkE, n_edges, gb);
  k_sort<<<nbuck, 512, 0, stream>>>(recs, bucket_base, sorted16, offsets, nbuck, n_nodes);
  k_gather<<<((size_t)n_nodes * 64 + 255) / 256, 256, 0, stream>>>(
      sorted16, offsets, h16, out, n_nodes);
}

// Round 5
// 160.550 us; speedup vs baseline: 1.0605x; 1.0605x over previous
//
#include <hip/hip_runtime.h>
#include <hip/hip_bf16.h>

#define IN_FEAT 128
#define N_HEADS 4
#define OUT_FEAT 16
#define HF 64  // N_HEADS * OUT_FEAT
#define NEG_SLOPE 0.2f

#define BSHIFT 7                 // 128 nodes per bucket
#define BNODES 128
#define NBUCK_MAX 512            // >= ceil(50000/128)=391

typedef __hip_bfloat16 bf16;
typedef __attribute__((ext_vector_type(8))) short short8;
typedef __attribute__((ext_vector_type(4))) float f32x4;

__device__ inline unsigned short f2b(float f) {
  bf16 b = __float2bfloat16(f);
  return *(unsigned short*)&b;
}
__device__ inline float b2f(unsigned short u) {
  return __uint_as_float((unsigned)u << 16);
}

// ---------------------------------------------------------------------------
// Kernel 1: h = x @ W via bf16 MFMA + fused LDS bucket histogram (no global
// atomics). Block = 256 thr = 4 waves = 64 nodes. Edge chunking by blockIdx
// over the gemm grid (gb blocks) MUST match k_part.
// ---------------------------------------------------------------------------
__global__ __launch_bounds__(256) void k_gemm(
    const float* __restrict__ x, const float* __restrict__ W,
    const float* __restrict__ a, unsigned short* __restrict__ h16,
    float* __restrict__ e_src, float* __restrict__ e_dst,
    const int* __restrict__ dst, int* __restrict__ bh,
    int n_nodes, int n_edges, int nbuck, int chunkE, int gb) {
  __shared__ unsigned short xs[64][136];
  __shared__ unsigned short wt[64][136];
  __shared__ unsigned short sh[64][68];
  __shared__ int bhist[NBUCK_MAX];
  const int t = threadIdx.x;
  const int nb = blockIdx.x * 64;
  const int lane = t & 63;
  const int w = t >> 6;

  for (int i = t; i < NBUCK_MAX; i += 256) bhist[i] = 0;

  const float4* x4 = (const float4*)x;
  for (int i = t; i < 64 * 32; i += 256) {
    int n = i >> 5, k4 = i & 31;
    int gn = nb + n;
    float4 v = (gn < n_nodes) ? x4[(size_t)gn * 32 + k4]
                              : make_float4(0.f, 0.f, 0.f, 0.f);
    ushort4 u;
    u.x = f2b(v.x); u.y = f2b(v.y); u.z = f2b(v.z); u.w = f2b(v.w);
    *(ushort4*)&xs[n][k4 * 4] = u;
  }
  for (int i = t; i < IN_FEAT * HF; i += 256) {
    int k = i >> 6, c = i & 63;
    wt[c][k] = f2b(W[i]);
  }
  __syncthreads();

  const int m = lane & 15;
  const int q = lane >> 4;
  f32x4 acc[4];
#pragma unroll
  for (int nt = 0; nt < 4; ++nt) acc[nt] = (f32x4){0.f, 0.f, 0.f, 0.f};

#pragma unroll
  for (int kc = 0; kc < 4; ++kc) {
    short8 af = *(const short8*)&xs[w * 16 + m][kc * 32 + q * 8];
#pragma unroll
    for (int nt = 0; nt < 4; ++nt) {
      short8 bfr = *(const short8*)&wt[nt * 16 + m][kc * 32 + q * 8];
      acc[nt] = __builtin_amdgcn_mfma_f32_16x16x32_bf16(af, bfr, acc[nt], 0, 0, 0);
    }
  }

#pragma unroll
  for (int nt = 0; nt < 4; ++nt)
#pragma unroll
    for (int r = 0; r < 4; ++r)
      sh[w * 16 + q * 4 + r][nt * 16 + m] = f2b(acc[nt][r]);
  __syncthreads();

  {
    int n = t >> 2, hd = t & 3;
    int gn = nb + n;
    if (gn < n_nodes) {
      float es = 0.f, ed = 0.f;
#pragma unroll
      for (int f = 0; f < OUT_FEAT; ++f) {
        float hv = b2f(sh[n][hd * 16 + f]);
        es = fmaf(hv, a[hd * 2 * OUT_FEAT + f], es);
        ed = fmaf(hv, a[hd * 2 * OUT_FEAT + OUT_FEAT + f], ed);
      }
      e_src[gn * N_HEADS + hd] = es;
      e_dst[gn * N_HEADS + hd] = ed;
    }
  }

  for (int i = t; i < 64 * 16; i += 256) {
    int n = i >> 4, c4 = (i & 15) * 4;
    int gn = nb + n;
    if (gn < n_nodes) {
      ushort4 v;
      v.x = sh[n][c4 + 0]; v.y = sh[n][c4 + 1];
      v.z = sh[n][c4 + 2]; v.w = sh[n][c4 + 3];
      *(ushort4*)(h16 + (size_t)gn * HF + c4) = v;
    }
  }

  // Fused bucket histogram (LDS atomics only) on this block's edge chunk.
  {
    int ebeg = blockIdx.x * chunkE;
    int eend = min(ebeg + chunkE, n_edges);
    for (int e = ebeg + t; e < eend; e += 256)
      atomicAdd(&bhist[dst[e] >> BSHIFT], 1);
    __syncthreads();
    for (int k = t; k < nbuck; k += 256)
      bh[(size_t)k * gb + blockIdx.x] = bhist[k];
  }
}

// ---------------------------------------------------------------------------
// scanA: one block per bucket; parallel exclusive scan of bh[k][0..gb) over
// the gb edge-chunk blocks -> sbase[k][b], and bucket total -> tot[k].
// ---------------------------------------------------------------------------
__global__ __launch_bounds__(1024) void k_scanA(
    const int* __restrict__ bh, int* __restrict__ sbase, int* __restrict__ tot,
    int gb) {
  __shared__ int s[1024];
  int t = threadIdx.x, k = blockIdx.x;
  int v = (t < gb) ? bh[(size_t)k * gb + t] : 0;
  s[t] = v;
  __syncthreads();
  for (int off = 1; off < 1024; off <<= 1) {
    int u = (t >= off) ? s[t - off] : 0;
    __syncthreads();
    s[t] += u;
    __syncthreads();
  }
  if (t < gb) sbase[(size_t)k * gb + t] = s[t] - v;
  if (t == 1023) tot[k] = s[t];
}

// ---------------------------------------------------------------------------
// scanB: single block; exclusive scan of bucket totals -> bucket_base.
// ---------------------------------------------------------------------------
__global__ __launch_bounds__(512) void k_scanB(
    const int* __restrict__ tot, int* __restrict__ bucket_base,
    int* __restrict__ offsets, int nbuck, int n_edges, int n_nodes) {
  __shared__ int s[512];
  int t = threadIdx.x;
  int v = (t < nbuck) ? tot[t] : 0;
  s[t] = v;
  __syncthreads();
  for (int off = 1; off < 512; off <<= 1) {
    int u = (t >= off) ? s[t - off] : 0;
    __syncthreads();
    s[t] += u;
    __syncthreads();
  }
  if (t < nbuck) bucket_base[t] = s[t] - v;
  if (t == 0) {
    bucket_base[nbuck] = n_edges;
    offsets[n_nodes] = n_edges;
  }
}

// ---------------------------------------------------------------------------
// Partition: softmax alpha per edge, scatter one 16B record
// {src, d&127, alpha_lo, alpha_hi} to its bucket-exact slot. LDS cursors
// pre-reserved from bucket_base + sbase — ZERO global atomics. Same gb-block
// chunking as k_gemm's histogram.
// ---------------------------------------------------------------------------
__global__ __launch_bounds__(256) void k_part(
    const int* __restrict__ src, const int* __restrict__ dst,
    const float* __restrict__ e_src, const float* __restrict__ e_dst,
    const int* __restrict__ bucket_base, const int* __restrict__ sbase,
    uint4* __restrict__ recs, int nbuck, int chunkE, int n_edges, int gb) {
  __shared__ int cur[NBUCK_MAX];
  int t = threadIdx.x;
  for (int k = t; k < nbuck; k += 256)
    cur[k] = bucket_base[k] + sbase[(size_t)k * gb + blockIdx.x];
  __syncthreads();
  int beg = blockIdx.x * chunkE;
  int end = min(beg + chunkE, n_edges);
  for (int e = beg + t; e < end; e += 256) {
    int s = src[e], d = dst[e];
    float4 es = ((const float4*)e_src)[s];
    float4 ed = ((const float4*)e_dst)[d];
    float v0 = es.x + ed.x, v1 = es.y + ed.y, v2 = es.z + ed.z, v3 = es.w + ed.w;
    v0 = (v0 > 0.f) ? v0 : NEG_SLOPE * v0;
    v1 = (v1 > 0.f) ? v1 : NEG_SLOPE * v1;
    v2 = (v2 > 0.f) ? v2 : NEG_SLOPE * v2;
    v3 = (v3 > 0.f) ? v3 : NEG_SLOPE * v3;
    float m = fmaxf(fmaxf(v0, v1), fmaxf(v2, v3));
    float e0 = __expf(v0 - m), e1 = __expf(v1 - m);
    float e2 = __expf(v2 - m), e3 = __expf(v3 - m);
    float inv = 1.f / (e0 + e1 + e2 + e3);
    unsigned lo = (unsigned)f2b(e0 * inv) | ((unsigned)f2b(e1 * inv) << 16);
    unsigned hi = (unsigned)f2b(e2 * inv) | ((unsigned)f2b(e3 * inv) << 16);
    int pos = atomicAdd(&cur[d >> BSHIFT], 1);
    recs[pos] = make_uint4((unsigned)s, (unsigned)(d & (BNODES - 1)), lo, hi);
  }
}

// ---------------------------------------------------------------------------
// Within-bucket counting sort by 7-bit local dst: LDS 128-bin histogram +
// scan + scatter into combined 16B records sorted16 = {src,0,alpha_lo,hi};
// also emits per-node offsets. Scattered writes land in an L2-resident
// 32KB window. LDS atomics only. Both passes unrolled 4-deep for MLP.
// ---------------------------------------------------------------------------
__global__ __launch_bounds__(512) void k_sort(
    const uint4* __restrict__ recs, const int* __restrict__ bucket_base,
    uint4* __restrict__ sorted16, int* __restrict__ offsets,
    int nbuck, int n_nodes) {
  __shared__ int hist[BNODES];
  __shared__ int cur[BNODES];
  int t = threadIdx.x, k = blockIdx.x;
  int beg = bucket_base[k];
  int n = bucket_base[k + 1] - beg;
  if (t < BNODES) hist[t] = 0;
  __syncthreads();
  {
    int j = t;
    for (; j + 1536 < n; j += 2048) {
      unsigned y0 = recs[beg + j].y;
      unsigned y1 = recs[beg + j + 512].y;
      unsigned y2 = recs[beg + j + 1024].y;
      unsigned y3 = recs[beg + j + 1536].y;
      atomicAdd(&hist[y0], 1);
      atomicAdd(&hist[y1], 1);
      atomicAdd(&hist[y2], 1);
      atomicAdd(&hist[y3], 1);
    }
    for (; j < n; j += 512) atomicAdd(&hist[recs[beg + j].y], 1);
  }
  __syncthreads();
  int v = (t < BNODES) ? hist[t] : 0;
  for (int off = 1; off < BNODES; off <<= 1) {
    int u = (t < BNODES && t >= off) ? hist[t - off] : 0;
    __syncthreads();
    if (t < BNODES) hist[t] += u;
    __syncthreads();
  }
  if (t < BNODES) {
    int pos = beg + hist[t] - v;  // exclusive
    cur[t] = pos;
    int node = (k << BSHIFT) + t;
    if (node < n_nodes) offsets[node] = pos;
  }
  __syncthreads();
  {
    int j = t;
    for (; j + 1536 < n; j += 2048) {
      uint4 r0 = recs[beg + j];
      uint4 r1 = recs[beg + j + 512];
      uint4 r2 = recs[beg + j + 1024];
      uint4 r3 = recs[beg + j + 1536];
      int p0 = atomicAdd(&cur[r0.y], 1);
      int p1 = atomicAdd(&cur[r1.y], 1);
      int p2 = atomicAdd(&cur[r2.y], 1);
      int p3 = atomicAdd(&cur[r3.y], 1);
      sorted16[p0] = make_uint4(r0.x, 0u, r0.z, r0.w);
      sorted16[p1] = make_uint4(r1.x, 0u, r1.z, r1.w);
      sorted16[p2] = make_uint4(r2.x, 0u, r2.z, r2.w);
      sorted16[p3] = make_uint4(r3.x, 0u, r3.z, r3.w);
    }
    for (; j < n; j += 512) {
      uint4 r = recs[beg + j];
      int p = atomicAdd(&cur[r.y], 1);
      sorted16[p] = make_uint4(r.x, 0u, r.z, r.w);
    }
  }
}

// ---------------------------------------------------------------------------
// Gather: one wave per dst node, TWO edges per wave-iteration.
// Lanes 0-31 take even edges, 32-63 odd edges; each lane covers a feature
// PAIR via one uint load (so each row-read instruction fetches TWO 128B
// rows, one per half-wave). Unroll 8 pairs = 16 edges per dependent-load
// batch -> a typical degree-16 node completes in ONE batch. Guarded loads
// (alpha forced 0) subsume the tail. Final __shfl_xor(·,32) merges
// parities; half 0 stores a coalesced float2.
// ---------------------------------------------------------------------------
__global__ __launch_bounds__(256) void k_gather(
    const uint4* __restrict__ sorted16, const int* __restrict__ offsets,
    const unsigned short* __restrict__ h16, float* __restrict__ out,
    int n_nodes) {
  int gid = blockIdx.x * 256 + threadIdx.x;
  int d = gid >> 6;
  if (d >= n_nodes) return;
  int lane = threadIdx.x & 63;
  int half = lane >> 5;          // edge parity
  int c2 = lane & 31;            // feature pair: features 2c2, 2c2+1
  unsigned sel = (unsigned)(c2 >> 3);      // head index 0..3
  unsigned shamt = (sel & 1u) * 16u;
  int beg = offsets[d];
  int end = offsets[d + 1];
  const unsigned* h32 = (const unsigned*)h16;
  float a0 = 0.f, a1 = 0.f;
  for (int j = beg; j < end; j += 16) {
    uint4 r[8];
#pragma unroll
    for (int k = 0; k < 8; ++k) {
      int idx = j + 2 * k + half;
      int cidx = (idx < end) ? idx : (end - 1);
      r[k] = sorted16[cidx];
    }
    unsigned hv[8];
#pragma unroll
    for (int k = 0; k < 8; ++k)
      hv[k] = h32[(size_t)r[k].x * (HF / 2) + c2];
#pragma unroll
    for (int k = 0; k < 8; ++k) {
      int idx = j + 2 * k + half;
      unsigned wd = (sel & 2u) ? r[k].w : r[k].z;
      float al = __uint_as_float(((wd >> shamt) & 0xffffu) << 16);
      al = (idx < end) ? al : 0.f;
      a0 = fmaf(al, b2f((unsigned short)(hv[k] & 0xffffu)), a0);
      a1 = fmaf(al, b2f((unsigned short)(hv[k] >> 16)), a1);
    }
  }
  a0 += __shfl_xor(a0, 32);
  a1 += __shfl_xor(a1, 32);
  if (half == 0) {
    float2 v = make_float2(a0, a1);
    *(float2*)(out + (size_t)d * HF + 2 * c2) = v;
  }
}

extern "C" void kernel_launch(void* const* d_in, const int* in_sizes, int n_in,
                              void* d_out, int out_size, void* d_ws, size_t ws_size,
                              hipStream_t stream) {
  const float* x = (const float*)d_in[0];
  const int* ei = (const int*)d_in[1];
  const float* W = (const float*)d_in[2];
  const float* a = (const float*)d_in[3];
  float* out = (float*)d_out;

  const int n_nodes = in_sizes[0] / IN_FEAT;   // 50000
  const int n_edges = in_sizes[1] / 2;         // 800000
  const int* src = ei;
  const int* dst = ei + n_edges;

  const int nbuck = (n_nodes + BNODES - 1) >> BSHIFT;   // 391 (<= NBUCK_MAX)
  const int gb = (n_nodes + 63) / 64;                   // 782 (<= 1024 for scanA)
  const int chunkE = (n_edges + gb - 1) / gb;           // 1024

  char* ws = (char*)d_ws;
  size_t off = 0;
  uint4* recs = (uint4*)(ws + off);        off += (size_t)n_edges * 16;           // 12.8 MB
  uint4* sorted16 = (uint4*)(ws + off);    off += (size_t)n_edges * 16;           // 12.8 MB
  unsigned short* h16 = (unsigned short*)(ws + off); off += (size_t)n_nodes * HF * 2; // 6.4 MB
  float* e_src = (float*)(ws + off);       off += (size_t)n_nodes * N_HEADS * 4;  // 0.8 MB
  float* e_dst = (float*)(ws + off);       off += (size_t)n_nodes * N_HEADS * 4;  // 0.8 MB
  int* bh = (int*)(ws + off);              off += (size_t)NBUCK_MAX * gb * 4;     // 1.6 MB
  int* sbase = (int*)(ws + off);           off += (size_t)NBUCK_MAX * gb * 4;     // 1.6 MB
  int* tot = (int*)(ws + off);             off += (size_t)NBUCK_MAX * 4;
  int* bucket_base = (int*)(ws + off);     off += (size_t)(NBUCK_MAX + 1) * 4;
  int* offsets = (int*)(ws + off);         off += ((size_t)n_nodes + 16) * 4;

  // Zero global atomics anywhere; no memsets (all buffers fully written
  // before read).
  k_gemm<<<gb, 256, 0, stream>>>(x, W, a, h16, e_src, e_dst, dst, bh,
                                 n_nodes, n_edges, nbuck, chunkE, gb);
  k_scanA<<<nbuck, 1024, 0, stream>>>(bh, sbase, tot, gb);
  k_scanB<<<1, 512, 0, stream>>>(tot, bucket_base, offsets, nbuck, n_edges, n_nodes);
  k_part<<<gb, 256, 0, stream>>>(src, dst, e_src, e_dst, bucket_base, sbase,
                                 recs, nbuck, chunkE, n_edges, gb);
  k_sort<<<nbuck, 512, 0, stream>>>(recs, bucket_base, sorted16, offsets, nbuck, n_nodes);
  k_gather<<<((size_t)n_nodes * 64 + 255) / 256, 256, 0, stream>>>(
      sorted16, offsets, h16, out, n_nodes);
}